// Round 11
// baseline (261.002 us; speedup 1.0000x reference)
//
#include <hip/hip_runtime.h>
#include <hip/hip_bf16.h>

// Problem constants
#define BB 4
#define LL 4096
#define DD 256
#define MM (BB * LL)              // 16384 rows total
#define NSPLIT 16
#define BM 512                    // query rows per attn block (8 consumer waves x 64 rows)
#define NQB (LL / BM)             // 8 query blocks per batch
#define KPS (LL / NSPLIT)         // 256 keys per split
#define KT 32                     // keys per ring tile (32 x 512B = 16KB)
#define NT (KPS / KT)             // 8 tiles
#define NSLOT 3                   // ring depth (3 x 16KB = 48KB LDS -> 2 blocks/CU)

typedef short short8 __attribute__((ext_vector_type(8)));   // 8 bf16 (4 VGPRs)
typedef float floatx4 __attribute__((ext_vector_type(4)));

#define SCALE_LOG2E 14.426950408889634f   // INV_TEMP * log2(e)

__device__ __forceinline__ unsigned short f2bf(float f) {
    __hip_bfloat16 h = __float2bfloat16(f);
    union { __hip_bfloat16 h; unsigned short s; } c; c.h = h; return c.s;
}

__device__ __forceinline__ float fast_exp2(float x) {
#if __has_builtin(__builtin_amdgcn_exp2f)
    return __builtin_amdgcn_exp2f(x);
#else
    return exp2f(x);
#endif
}

// Stage 16B/lane global -> LDS (wave-uniform LDS base; lane i -> l + i*16).
__device__ __forceinline__ void stage16(const char* g, char* l, int lane) {
#if __has_builtin(__builtin_amdgcn_global_load_lds)
    __builtin_amdgcn_global_load_lds(
        (const __attribute__((address_space(1))) void*)(g + lane * 16),
        (__attribute__((address_space(3))) void*)l, 16, 0, 0);
#else
    *(short8*)(l + lane * 16) = *(const short8*)(g + lane * 16);
#endif
}

// Fragment-major chunk address (16B units): row-group r16 = row/16, chunk kk,
// quad q, lane-row n15. Used for BOTH qn and kn. Bytes of one r16 group are
// contiguous (8KB), so a 32-row tile = 16KB linear.
__device__ __forceinline__ const short8* frag_ptr(const char* base, int r16, int kk, int q, int n15) {
    return (const short8*)(base + ((((size_t)r16 * 8 + kk) * 4 + q) * 16 + n15) * 16);
}

// ---------------------------------------------------------------------------
// Kernel 0: W f32 -> bf16 with XOR chunk swizzle (chunk c of row r stored at
// c ^ (r&7)). Blocks 0..31 convert Wq, 32..63 convert Wk.
// ---------------------------------------------------------------------------
__global__ __launch_bounds__(256) void cvt_swz_kernel(
    const float* __restrict__ srcq, const float* __restrict__ srck,
    unsigned short* __restrict__ dstq, unsigned short* __restrict__ dstk)
{
    const int which = blockIdx.x >> 5;
    const float* src = which ? srck : srcq;
    unsigned short* dst = which ? dstk : dstq;
    const int t = (blockIdx.x & 31) * 256 + threadIdx.x;
    const int r = t >> 5, c = t & 31;
    const float4 v0 = ((const float4*)src)[t * 2];
    const float4 v1 = ((const float4*)src)[t * 2 + 1];
    short8 o;
    o[0] = (short)f2bf(v0.x); o[1] = (short)f2bf(v0.y);
    o[2] = (short)f2bf(v0.z); o[3] = (short)f2bf(v0.w);
    o[4] = (short)f2bf(v1.x); o[5] = (short)f2bf(v1.y);
    o[6] = (short)f2bf(v1.z); o[7] = (short)f2bf(v1.w);
    const int cs = c ^ (r & 7);
    *(short8*)(dst + (size_t)r * DD + cs * 8) = o;
}

// ---------------------------------------------------------------------------
// Kernel A: one pass (q or k) per block; 512 blocks = (row-block of 64, pass).
// W staged through LDS (double-buffered, global_load_lds) from pre-swizzled W.
// BOTH outputs stored FRAGMENT-MAJOR (see frag_ptr). qn pre-scaled by
// SCALE_LOG2E. MFMA 16x16x32 bf16; A: m=lane&15,k=quad*8+j;
// B: n=lane&15,k=quad*8+j; C/D: col=lane&15, row=quad*4+reg.
// ---------------------------------------------------------------------------
__global__ __launch_bounds__(256) void proj_norm_kernel(
    const float* __restrict__ latents,
    const __hip_bfloat16* __restrict__ Wq,
    const __hip_bfloat16* __restrict__ Wk,
    __hip_bfloat16* __restrict__ qn,
    __hip_bfloat16* __restrict__ kn)
{
    __shared__ char lds[65536];   // 2 x 32KB W double-buffer; reused for transpose

    const int tid  = threadIdx.x;
    const int wave = tid >> 6;
    const int lane = tid & 63;
    const int n15  = lane & 15;
    const int quad = lane >> 4;
    const int sw   = n15 & 7;

    const int pass  = blockIdx.x & 1;
    const int rbase = (blockIdx.x >> 1) * 64;
    const int m0    = rbase + wave * 16;
    const int r160  = rbase >> 4;

    // A fragments: 16 rows x K=256, f32 loaded, converted in-register
    short8 afrag[8];
    const float* Abase = latents + (size_t)(m0 + n15) * DD + quad * 8;
#pragma unroll
    for (int kk = 0; kk < 8; ++kk) {
        const float4 v0 = *(const float4*)(Abase + kk * 32);
        const float4 v1 = *(const float4*)(Abase + kk * 32 + 4);
        short8 f;
        f[0] = (short)f2bf(v0.x); f[1] = (short)f2bf(v0.y);
        f[2] = (short)f2bf(v0.z); f[3] = (short)f2bf(v0.w);
        f[4] = (short)f2bf(v1.x); f[5] = (short)f2bf(v1.y);
        f[6] = (short)f2bf(v1.z); f[7] = (short)f2bf(v1.w);
        afrag[kk] = f;
    }

    const char* W = (const char*)(pass ? Wk : Wq);

    floatx4 acc[16];
#pragma unroll
    for (int ct = 0; ct < 16; ++ct) acc[ct] = (floatx4){0.f, 0.f, 0.f, 0.f};

    // Pre-stage round 0 into buf 0
    {
        const char* src = W + wave * 8192;
        char* dst = lds + wave * 8192;
#pragma unroll
        for (int j = 0; j < 8; ++j) stage16(src + j * 1024, dst + j * 1024, lane);
    }

    for (int round = 0; round < 4; ++round) {
        __syncthreads();    // own-wave vmcnt drained -> buf (round&1) ready
        if (round + 1 < 4) {
            const char* src = W + (size_t)(round + 1) * 32768 + wave * 8192;
            char* dst = lds + ((round + 1) & 1) * 32768 + wave * 8192;
#pragma unroll
            for (int j = 0; j < 8; ++j) stage16(src + j * 1024, dst + j * 1024, lane);
        }
        const char* buf = lds + (round & 1) * 32768;
#pragma unroll
        for (int jt = 0; jt < 4; ++jt) {
            const int ct = round * 4 + jt;
            const char* lbase = buf + (jt * 16 + n15) * 512;
            floatx4 a = acc[ct];
#pragma unroll
            for (int kk = 0; kk < 8; ++kk) {
                const int chunk = (4 * kk + quad) ^ sw;
                short8 bfr = *(const short8*)(lbase + chunk * 16);
                a = __builtin_amdgcn_mfma_f32_16x16x32_bf16(afrag[kk], bfr, a, 0, 0, 0);
            }
            acc[ct] = a;
        }
    }

    // Row norms (rows = quad*4 + r)
    float ss[4] = {0.f, 0.f, 0.f, 0.f};
#pragma unroll
    for (int ct = 0; ct < 16; ++ct)
#pragma unroll
        for (int r = 0; r < 4; ++r) ss[r] += acc[ct][r] * acc[ct][r];
#pragma unroll
    for (int r = 0; r < 4; ++r) {
        ss[r] += __shfl_xor(ss[r], 1, 64);
        ss[r] += __shfl_xor(ss[r], 2, 64);
        ss[r] += __shfl_xor(ss[r], 4, 64);
        ss[r] += __shfl_xor(ss[r], 8, 64);
    }
    float sc[4];
#pragma unroll
    for (int r = 0; r < 4; ++r) {
        sc[r] = 1.f / fmaxf(sqrtf(ss[r]), 1e-12f);
        if (pass == 0) sc[r] *= SCALE_LOG2E;   // fold softmax scale into qn
    }

    __hip_bfloat16* outp = pass ? kn : qn;

    // Epilogue: LDS transpose (64 rows x 136-el padded bf16) then coalesced
    // fragment-major 16B stores. Two halves of 128 cols each.
    unsigned short* tb = (unsigned short*)lds;
#pragma unroll
    for (int h = 0; h < 2; ++h) {
        __syncthreads();   // previous lds users done
#pragma unroll
        for (int cth = 0; cth < 8; ++cth) {
            const int ct = h * 8 + cth;
            const int col = cth * 16 + n15;
#pragma unroll
            for (int r = 0; r < 4; ++r) {
                const int rl = wave * 16 + quad * 4 + r;
                tb[rl * 136 + col] = f2bf(acc[ct][r] * sc[r]);
            }
        }
        __syncthreads();
#pragma unroll
        for (int j = 0; j < 4; ++j) {
            const int g = tid + j * 256;
            const int n15r = g & 15, q2 = (g >> 4) & 3, kkh = (g >> 6) & 3, r16l = (g >> 8) & 3;
            const int rl = r16l * 16 + n15r;
            short8 v = *(const short8*)(tb + rl * 136 + kkh * 32 + q2 * 8);
            const size_t chunk = (((size_t)(r160 + r16l) * 8 + (h * 4 + kkh)) * 4 + q2) * 16 + n15r;
            *(short8*)((char*)outp + chunk * 16) = v;
        }
    }
}

// ---------------------------------------------------------------------------
// Kernel B: PRODUCER-CONSUMER flash attention (no per-tile barriers).
// 576 threads = 8 consumer waves (64 q-rows each -> 4 MFMA per B-read) + 1
// producer wave. 512 blocks = 2/CU (ring 3 x 16KB = 49.2KB LDS, VGPR ~222
// -> 4.5 waves/SIMD for chain overlap). Producer: poll consumed ->
// global_load_lds 16KB -> s_waitcnt vmcnt(0) (stalls producer ONLY) ->
// release ready. Consumers: acquire-poll ready -> ds_read+MFMA -> fetch_add
// consumed. Single initial __syncthreads; no vmcnt(0)-at-barrier drain.
// e = exp2(acc) (qn pre-scaled; ref's clip(+-50) is a no-op: |q.k| <= 1).
// ---------------------------------------------------------------------------
__global__ __launch_bounds__(576) void attn_kernel(
    const __hip_bfloat16* __restrict__ qn,
    const __hip_bfloat16* __restrict__ kn,
    const float* __restrict__ coords,
    float* __restrict__ partials)
{
    __shared__ char ring[NSLOT * 16384];
    __shared__ unsigned int rdy[NSLOT];
    __shared__ unsigned int con[NSLOT];

    const int tid  = threadIdx.x;
    const int wave = tid >> 6;
    const int lane = tid & 63;
    const int n15  = lane & 15;
    const int quad = lane >> 4;

    if (tid < NSLOT) { rdy[tid] = 0u; con[tid] = 0u; }
    __syncthreads();   // only barrier in the kernel

    int bs = blockIdx.x;
    const int qb    = bs % NQB;    bs /= NQB;   // consecutive blocks share (b,split) kn slice
    const int split = bs % NSPLIT; bs /= NSPLIT;
    const int b     = bs;

    const int key_base = b * LL + split * KPS;
    const char* ksrc = (const char*)kn + (size_t)(key_base >> 4) * 8192;  // frag-major bytes

    if (wave == 8) {
        // ---------------- producer ----------------
        for (int t = 0; t < NT; ++t) {
            const int s = t % NSLOT;
            if (t >= NSLOT) {
                const unsigned target = 8u * (unsigned)(t / NSLOT);
                while (__hip_atomic_load(&con[s], __ATOMIC_ACQUIRE, __HIP_MEMORY_SCOPE_WORKGROUP) < target)
                    __builtin_amdgcn_s_sleep(2);
            }
            const char* src = ksrc + (size_t)t * 16384;
            char* dst = ring + s * 16384;
#pragma unroll
            for (int j = 0; j < 16; ++j) stage16(src + j * 1024, dst + j * 1024, lane);
            asm volatile("s_waitcnt vmcnt(0)" ::: "memory");
            __hip_atomic_store(&rdy[s], (unsigned)(t + 1), __ATOMIC_RELEASE, __HIP_MEMORY_SCOPE_WORKGROUP);
        }
        return;
    }

    // ---------------- consumers (waves 0..7, 64 q-rows each) ----------------
    const int mw = b * LL + qb * BM + wave * 64;
    const char* qf = (const char*)qn;

    short8 aq[4][8];
    const int t16 = mw >> 4;
#pragma unroll
    for (int rt = 0; rt < 4; ++rt)
#pragma unroll
        for (int kk = 0; kk < 8; ++kk)
            aq[rt][kk] = *frag_ptr(qf, t16 + rt, kk, quad, n15);

    float s0[4][4], s1[4][4], s2[4][4];
#pragma unroll
    for (int rt = 0; rt < 4; ++rt)
#pragma unroll
        for (int r = 0; r < 4; ++r) { s0[rt][r] = 0.f; s1[rt][r] = 0.f; s2[rt][r] = 0.f; }

    // coords prefetch, one tile ahead (2 x 16 keys per tile)
    float2 ccv[2];
#pragma unroll
    for (int ct = 0; ct < 2; ++ct)
        ccv[ct] = *(const float2*)(coords + (size_t)(key_base + ct * 16 + n15) * 2);

    for (int t = 0; t < NT; ++t) {
        const int s = t % NSLOT;
        while (__hip_atomic_load(&rdy[s], __ATOMIC_ACQUIRE, __HIP_MEMORY_SCOPE_WORKGROUP) < (unsigned)(t + 1))
            __builtin_amdgcn_s_sleep(1);
        const char* buf = ring + s * 16384;

#pragma unroll
        for (int ct = 0; ct < 2; ++ct) {
            const float2 cur = ccv[ct];
            if (t + 1 < NT)
                ccv[ct] = *(const float2*)(coords + (size_t)(key_base + (t + 1) * KT + ct * 16 + n15) * 2);

            floatx4 acc[4];
#pragma unroll
            for (int rt = 0; rt < 4; ++rt) acc[rt] = (floatx4){0.f, 0.f, 0.f, 0.f};
            const char* lbase = buf + ct * 8192 + quad * 256 + n15 * 16;
#pragma unroll
            for (int kk = 0; kk < 8; ++kk) {
                short8 bfr = *(const short8*)(lbase + kk * 1024);
#pragma unroll
                for (int rt = 0; rt < 4; ++rt)
                    acc[rt] = __builtin_amdgcn_mfma_f32_16x16x32_bf16(aq[rt][kk], bfr, acc[rt], 0, 0, 0);
            }
#pragma unroll
            for (int rt = 0; rt < 4; ++rt)
#pragma unroll
                for (int r = 0; r < 4; ++r) {
                    const float e = fast_exp2(acc[rt][r]);
                    s0[rt][r] += e;
                    s1[rt][r] = fmaf(cur.x, e, s1[rt][r]);
                    s2[rt][r] = fmaf(cur.y, e, s2[rt][r]);
                }
        }
        // release: all our ds_reads of this slot precede this
        __hip_atomic_fetch_add(&con[s], 1u, __ATOMIC_RELEASE, __HIP_MEMORY_SCOPE_WORKGROUP);
    }

    // Reduce across the 16 lanes of each quad
#pragma unroll
    for (int rt = 0; rt < 4; ++rt)
#pragma unroll
        for (int r = 0; r < 4; ++r)
#pragma unroll
            for (int mask = 1; mask <= 8; mask <<= 1) {
                s0[rt][r] += __shfl_xor(s0[rt][r], mask, 64);
                s1[rt][r] += __shfl_xor(s1[rt][r], mask, 64);
                s2[rt][r] += __shfl_xor(s2[rt][r], mask, 64);
            }

    if (n15 == 0) {
#pragma unroll
        for (int rt = 0; rt < 4; ++rt)
#pragma unroll
            for (int r = 0; r < 4; ++r) {
                const int m = mw + rt * 16 + quad * 4 + r;
                float* p = partials + ((size_t)split * MM + m) * 4;
                p[0] = s0[rt][r];
                p[1] = s1[rt][r];
                p[2] = s2[rt][r];
            }
    }
}

// ---------------------------------------------------------------------------
// Kernel C: combine splits, alpha blend, emit new_coords + displacement (f32).
// ---------------------------------------------------------------------------
__global__ __launch_bounds__(256) void finish_kernel(
    const float* __restrict__ partials,
    const float* __restrict__ coords,
    const float* __restrict__ alpha_raw,
    float* __restrict__ out)
{
    const int m = blockIdx.x * 256 + threadIdx.x;

    const float alpha = 1.f / (1.f + __expf(-alpha_raw[0]));

    float s0 = 0.f, s1 = 0.f, s2 = 0.f;
#pragma unroll
    for (int s = 0; s < NSPLIT; ++s) {
        const float4 v = *(const float4*)(partials + ((size_t)s * MM + m) * 4);
        s0 += v.x; s1 += v.y; s2 += v.z;
    }

    const float cx = coords[m * 2];
    const float cy = coords[m * 2 + 1];
    const float inv = 1.f / s0;
    const float nx = alpha * (s1 * inv) + (1.f - alpha) * cx;
    const float ny = alpha * (s2 * inv) + (1.f - alpha) * cy;

    out[m * 2]     = nx;
    out[m * 2 + 1] = ny;
    out[2 * MM + m * 2]     = nx - cx;
    out[2 * MM + m * 2 + 1] = ny - cy;
}

extern "C" void kernel_launch(void* const* d_in, const int* in_sizes, int n_in,
                              void* d_out, int out_size, void* d_ws, size_t ws_size,
                              hipStream_t stream) {
    const float* latents   = (const float*)d_in[0];
    const float* coords    = (const float*)d_in[1];
    const float* Wq        = (const float*)d_in[2];
    const float* Wk        = (const float*)d_in[3];
    const float* alpha_raw = (const float*)d_in[4];
    // d_in[5] = layer_idx: selects weight set only; provided W's are the
    // pred_idx=1 params, so unused.

    char* ws = (char*)d_ws;
    __hip_bfloat16* qn   = (__hip_bfloat16*)ws;                                  // 8 MB (fragment-major)
    __hip_bfloat16* kn   = (__hip_bfloat16*)(ws + (size_t)8 * 1024 * 1024);      // 8 MB (fragment-major)
    __hip_bfloat16* wq_b = (__hip_bfloat16*)(ws + (size_t)16 * 1024 * 1024);     // 128 KB (swizzled)
    __hip_bfloat16* wk_b = (__hip_bfloat16*)(ws + (size_t)16 * 1024 * 1024 + 131072);
    float* partials      = (float*)(ws + (size_t)16 * 1024 * 1024 + 262144);     // 4 MB

    float* out = (float*)d_out;

    cvt_swz_kernel<<<64, 256, 0, stream>>>(Wq, Wk, (unsigned short*)wq_b, (unsigned short*)wk_b);
    proj_norm_kernel<<<512, 256, 0, stream>>>(latents, wq_b, wk_b, qn, kn);
    attn_kernel<<<BB * NQB * NSPLIT, 576, 0, stream>>>(qn, kn, coords, partials);
    finish_kernel<<<MM / 256, 256, 0, stream>>>(partials, coords, alpha_raw, out);
}

// Round 12
// 121.360 us; speedup vs baseline: 2.1506x; 2.1506x over previous
//
#include <hip/hip_runtime.h>
#include <hip/hip_bf16.h>

// Problem constants
#define BB 4
#define LL 4096
#define DD 256
#define MM (BB * LL)              // 16384 rows total
#define NSPLIT 8
#define BM 256                    // query rows per attn block (4 waves x 64 rows)
#define NQB (LL / BM)             // 16 query blocks per batch
#define KPS (LL / NSPLIT)         // 512 keys per split
#define KT 64                     // keys per LDS tile (64 x 512B = 32KB)
#define NKT (KPS / KT)            // 8

typedef short short8 __attribute__((ext_vector_type(8)));   // 8 bf16 (4 VGPRs)
typedef float floatx4 __attribute__((ext_vector_type(4)));

#define SCALE_LOG2E 14.426950408889634f   // INV_TEMP * log2(e)

__device__ __forceinline__ unsigned short f2bf(float f) {
    __hip_bfloat16 h = __float2bfloat16(f);
    union { __hip_bfloat16 h; unsigned short s; } c; c.h = h; return c.s;
}

__device__ __forceinline__ float fast_exp2(float x) {
#if __has_builtin(__builtin_amdgcn_exp2f)
    return __builtin_amdgcn_exp2f(x);
#else
    return exp2f(x);
#endif
}

// Stage 16B/lane global -> LDS (wave-uniform LDS base; lane i -> l + i*16).
__device__ __forceinline__ void stage16(const char* g, char* l, int lane) {
#if __has_builtin(__builtin_amdgcn_global_load_lds)
    __builtin_amdgcn_global_load_lds(
        (const __attribute__((address_space(1))) void*)(g + lane * 16),
        (__attribute__((address_space(3))) void*)l, 16, 0, 0);
#else
    *(short8*)(l + lane * 16) = *(const short8*)(g + lane * 16);
#endif
}

// Fragment-major chunk address (16B units): row-group r16 = row/16, chunk kk,
// quad q, lane-row n15. Used for BOTH qn and kn. Bytes of one r16 group are
// contiguous (8KB); a 64-row tile = 32KB linear (global_load_lds friendly,
// bank-conflict-free LDS reads: R10 measured SQ_LDS_BANK_CONFLICT=0... with
// per-wave b128 floor ~4cyc when multiple rt reads alias, acceptable).
__device__ __forceinline__ const short8* frag_ptr(const char* base, int r16, int kk, int q, int n15) {
    return (const short8*)(base + ((((size_t)r16 * 8 + kk) * 4 + q) * 16 + n15) * 16);
}

// ---------------------------------------------------------------------------
// Kernel 0: W f32 -> bf16 with XOR chunk swizzle (chunk c of row r stored at
// c ^ (r&7)). Blocks 0..31 convert Wq, 32..63 convert Wk.
// ---------------------------------------------------------------------------
__global__ __launch_bounds__(256) void cvt_swz_kernel(
    const float* __restrict__ srcq, const float* __restrict__ srck,
    unsigned short* __restrict__ dstq, unsigned short* __restrict__ dstk)
{
    const int which = blockIdx.x >> 5;
    const float* src = which ? srck : srcq;
    unsigned short* dst = which ? dstk : dstq;
    const int t = (blockIdx.x & 31) * 256 + threadIdx.x;
    const int r = t >> 5, c = t & 31;
    const float4 v0 = ((const float4*)src)[t * 2];
    const float4 v1 = ((const float4*)src)[t * 2 + 1];
    short8 o;
    o[0] = (short)f2bf(v0.x); o[1] = (short)f2bf(v0.y);
    o[2] = (short)f2bf(v0.z); o[3] = (short)f2bf(v0.w);
    o[4] = (short)f2bf(v1.x); o[5] = (short)f2bf(v1.y);
    o[6] = (short)f2bf(v1.z); o[7] = (short)f2bf(v1.w);
    const int cs = c ^ (r & 7);
    *(short8*)(dst + (size_t)r * DD + cs * 8) = o;
}

// ---------------------------------------------------------------------------
// Kernel A: one pass (q or k) per block; 512 blocks = (row-block of 64, pass).
// W staged through LDS (double-buffered, global_load_lds) from pre-swizzled W.
// BOTH outputs stored FRAGMENT-MAJOR (see frag_ptr). qn pre-scaled by
// SCALE_LOG2E. MFMA 16x16x32 bf16; A: m=lane&15,k=quad*8+j;
// B: n=lane&15,k=quad*8+j; C/D: col=lane&15, row=quad*4+reg.
// ---------------------------------------------------------------------------
__global__ __launch_bounds__(256) void proj_norm_kernel(
    const float* __restrict__ latents,
    const __hip_bfloat16* __restrict__ Wq,
    const __hip_bfloat16* __restrict__ Wk,
    __hip_bfloat16* __restrict__ qn,
    __hip_bfloat16* __restrict__ kn)
{
    __shared__ char lds[65536];   // 2 x 32KB W double-buffer; reused for transpose

    const int tid  = threadIdx.x;
    const int wave = tid >> 6;
    const int lane = tid & 63;
    const int n15  = lane & 15;
    const int quad = lane >> 4;
    const int sw   = n15 & 7;

    const int pass  = blockIdx.x & 1;
    const int rbase = (blockIdx.x >> 1) * 64;
    const int m0    = rbase + wave * 16;
    const int r160  = rbase >> 4;

    // A fragments: 16 rows x K=256, f32 loaded, converted in-register
    short8 afrag[8];
    const float* Abase = latents + (size_t)(m0 + n15) * DD + quad * 8;
#pragma unroll
    for (int kk = 0; kk < 8; ++kk) {
        const float4 v0 = *(const float4*)(Abase + kk * 32);
        const float4 v1 = *(const float4*)(Abase + kk * 32 + 4);
        short8 f;
        f[0] = (short)f2bf(v0.x); f[1] = (short)f2bf(v0.y);
        f[2] = (short)f2bf(v0.z); f[3] = (short)f2bf(v0.w);
        f[4] = (short)f2bf(v1.x); f[5] = (short)f2bf(v1.y);
        f[6] = (short)f2bf(v1.z); f[7] = (short)f2bf(v1.w);
        afrag[kk] = f;
    }

    const char* W = (const char*)(pass ? Wk : Wq);

    floatx4 acc[16];
#pragma unroll
    for (int ct = 0; ct < 16; ++ct) acc[ct] = (floatx4){0.f, 0.f, 0.f, 0.f};

    // Pre-stage round 0 into buf 0
    {
        const char* src = W + wave * 8192;
        char* dst = lds + wave * 8192;
#pragma unroll
        for (int j = 0; j < 8; ++j) stage16(src + j * 1024, dst + j * 1024, lane);
    }

    for (int round = 0; round < 4; ++round) {
        __syncthreads();    // own-wave vmcnt drained -> buf (round&1) ready
        if (round + 1 < 4) {
            const char* src = W + (size_t)(round + 1) * 32768 + wave * 8192;
            char* dst = lds + ((round + 1) & 1) * 32768 + wave * 8192;
#pragma unroll
            for (int j = 0; j < 8; ++j) stage16(src + j * 1024, dst + j * 1024, lane);
        }
        const char* buf = lds + (round & 1) * 32768;
#pragma unroll
        for (int jt = 0; jt < 4; ++jt) {
            const int ct = round * 4 + jt;
            const char* lbase = buf + (jt * 16 + n15) * 512;
            floatx4 a = acc[ct];
#pragma unroll
            for (int kk = 0; kk < 8; ++kk) {
                const int chunk = (4 * kk + quad) ^ sw;
                short8 bfr = *(const short8*)(lbase + chunk * 16);
                a = __builtin_amdgcn_mfma_f32_16x16x32_bf16(afrag[kk], bfr, a, 0, 0, 0);
            }
            acc[ct] = a;
        }
    }

    // Row norms (rows = quad*4 + r)
    float ss[4] = {0.f, 0.f, 0.f, 0.f};
#pragma unroll
    for (int ct = 0; ct < 16; ++ct)
#pragma unroll
        for (int r = 0; r < 4; ++r) ss[r] += acc[ct][r] * acc[ct][r];
#pragma unroll
    for (int r = 0; r < 4; ++r) {
        ss[r] += __shfl_xor(ss[r], 1, 64);
        ss[r] += __shfl_xor(ss[r], 2, 64);
        ss[r] += __shfl_xor(ss[r], 4, 64);
        ss[r] += __shfl_xor(ss[r], 8, 64);
    }
    float sc[4];
#pragma unroll
    for (int r = 0; r < 4; ++r) {
        sc[r] = 1.f / fmaxf(sqrtf(ss[r]), 1e-12f);
        if (pass == 0) sc[r] *= SCALE_LOG2E;   // fold softmax scale into qn
    }

    __hip_bfloat16* outp = pass ? kn : qn;

    // Epilogue: LDS transpose (64 rows x 136-el padded bf16) then coalesced
    // fragment-major 16B stores. Two halves of 128 cols each.
    unsigned short* tb = (unsigned short*)lds;
#pragma unroll
    for (int h = 0; h < 2; ++h) {
        __syncthreads();   // previous lds users done
#pragma unroll
        for (int cth = 0; cth < 8; ++cth) {
            const int ct = h * 8 + cth;
            const int col = cth * 16 + n15;
#pragma unroll
            for (int r = 0; r < 4; ++r) {
                const int rl = wave * 16 + quad * 4 + r;
                tb[rl * 136 + col] = f2bf(acc[ct][r] * sc[r]);
            }
        }
        __syncthreads();
#pragma unroll
        for (int j = 0; j < 4; ++j) {
            const int g = tid + j * 256;
            const int n15r = g & 15, q2 = (g >> 4) & 3, kkh = (g >> 6) & 3, r16l = (g >> 8) & 3;
            const int rl = r16l * 16 + n15r;
            short8 v = *(const short8*)(tb + rl * 136 + kkh * 32 + q2 * 8);
            const size_t chunk = (((size_t)(r160 + r16l) * 8 + (h * 4 + kkh)) * 4 + q2) * 16 + n15r;
            *(short8*)((char*)outp + chunk * 16) = v;
        }
    }
}

// ---------------------------------------------------------------------------
// Kernel B: flash attention sums — R7's proven dbuf/1-barrier-per-tile
// structure with rt=4 register reuse (4 waves x 64 q-rows, aq[4][8]; each LDS
// B-read feeds 4 MFMA -> LDS-read pipe halved vs R7). 256 threads,
// __launch_bounds__(256,2) = R8's proven no-spill register shape (Q-frags can
// sit in AGPRs via the gfx950 unified file). KT=64 dbuf (2x32KB LDS),
// NSPLIT=8 -> 512 blocks = 2/CU. e = exp2(acc) (qn pre-scaled; ref's
// clip(+-50) is a no-op since |q.k| <= 1 => |score| <= 10).
// ---------------------------------------------------------------------------
__global__ __launch_bounds__(256, 2) void attn_kernel(
    const __hip_bfloat16* __restrict__ qn,
    const __hip_bfloat16* __restrict__ kn,
    const float* __restrict__ coords,
    float* __restrict__ partials)
{
    __shared__ char lds[2 * 32768];

    const int tid  = threadIdx.x;
    const int wave = tid >> 6;
    const int lane = tid & 63;
    const int n15  = lane & 15;
    const int quad = lane >> 4;

    int bs = blockIdx.x;
    const int qb    = bs % NQB;    bs /= NQB;   // consecutive blocks share (b,split) kn slice
    const int split = bs % NSPLIT; bs /= NSPLIT;
    const int b     = bs;

    const int mw = b * LL + qb * BM + wave * 64;   // this wave's 64 q-rows
    const int key_base = b * LL + split * KPS;
    const char* ksrc = (const char*)kn + (size_t)(key_base >> 4) * 8192;  // frag-major bytes

    // Pre-stage tile 0 (4 waves x 8KB contiguous)
    {
        const char* src = ksrc + wave * 8192;
        char* dst = lds + wave * 8192;
#pragma unroll
        for (int j = 0; j < 8; ++j) stage16(src + j * 1024, dst + j * 1024, lane);
    }

    // Q fragments from fragment-major qn: fully coalesced 16B/lane loads
    short8 aq[4][8];
    const int t16 = mw >> 4;
#pragma unroll
    for (int rt = 0; rt < 4; ++rt)
#pragma unroll
        for (int kk = 0; kk < 8; ++kk)
            aq[rt][kk] = *frag_ptr((const char*)qn, t16 + rt, kk, quad, n15);

    float s0[4][4], s1[4][4], s2[4][4];
#pragma unroll
    for (int rt = 0; rt < 4; ++rt)
#pragma unroll
        for (int r = 0; r < 4; ++r) { s0[rt][r] = 0.f; s1[rt][r] = 0.f; s2[rt][r] = 0.f; }

    for (int kt = 0; kt < NKT; ++kt) {
        __syncthreads();   // own-wave vmcnt drained -> buf (kt&1) visible to all
        if (kt + 1 < NKT) {
            const char* src = ksrc + (size_t)(kt + 1) * KT * 512 + wave * 8192;
            char* dst = lds + ((kt + 1) & 1) * 32768 + wave * 8192;
#pragma unroll
            for (int j = 0; j < 8; ++j) stage16(src + j * 1024, dst + j * 1024, lane);
        }
        const char* buf = lds + (kt & 1) * 32768;

#pragma unroll
        for (int ct = 0; ct < 4; ++ct) {
            const int kidx = key_base + kt * KT + ct * 16 + n15;
            const float2 cur = *(const float2*)(coords + (size_t)kidx * 2);

            floatx4 acc[4];
#pragma unroll
            for (int rt = 0; rt < 4; ++rt) acc[rt] = (floatx4){0.f, 0.f, 0.f, 0.f};
            // fragment-major tile: 16-key group ct at byte offset ct*8192
            const char* lbase = buf + ct * 8192 + quad * 256 + n15 * 16;
#pragma unroll
            for (int kk = 0; kk < 8; ++kk) {
                short8 bfr = *(const short8*)(lbase + kk * 1024);
#pragma unroll
                for (int rt = 0; rt < 4; ++rt)
                    acc[rt] = __builtin_amdgcn_mfma_f32_16x16x32_bf16(aq[rt][kk], bfr, acc[rt], 0, 0, 0);
            }
#pragma unroll
            for (int rt = 0; rt < 4; ++rt)
#pragma unroll
                for (int r = 0; r < 4; ++r) {
                    const float e = fast_exp2(acc[rt][r]);
                    s0[rt][r] += e;
                    s1[rt][r] = fmaf(cur.x, e, s1[rt][r]);
                    s2[rt][r] = fmaf(cur.y, e, s2[rt][r]);
                }
        }
    }

    // Reduce across the 16 lanes of each quad
#pragma unroll
    for (int rt = 0; rt < 4; ++rt)
#pragma unroll
        for (int r = 0; r < 4; ++r)
#pragma unroll
            for (int mask = 1; mask <= 8; mask <<= 1) {
                s0[rt][r] += __shfl_xor(s0[rt][r], mask, 64);
                s1[rt][r] += __shfl_xor(s1[rt][r], mask, 64);
                s2[rt][r] += __shfl_xor(s2[rt][r], mask, 64);
            }

    if (n15 == 0) {
#pragma unroll
        for (int rt = 0; rt < 4; ++rt)
#pragma unroll
            for (int r = 0; r < 4; ++r) {
                const int m = mw + rt * 16 + quad * 4 + r;
                float* p = partials + ((size_t)split * MM + m) * 4;
                p[0] = s0[rt][r];
                p[1] = s1[rt][r];
                p[2] = s2[rt][r];
            }
    }
}

// ---------------------------------------------------------------------------
// Kernel C: combine splits, alpha blend, emit new_coords + displacement (f32).
// ---------------------------------------------------------------------------
__global__ __launch_bounds__(256) void finish_kernel(
    const float* __restrict__ partials,
    const float* __restrict__ coords,
    const float* __restrict__ alpha_raw,
    float* __restrict__ out)
{
    const int m = blockIdx.x * 256 + threadIdx.x;

    const float alpha = 1.f / (1.f + __expf(-alpha_raw[0]));

    float s0 = 0.f, s1 = 0.f, s2 = 0.f;
#pragma unroll
    for (int s = 0; s < NSPLIT; ++s) {
        const float4 v = *(const float4*)(partials + ((size_t)s * MM + m) * 4);
        s0 += v.x; s1 += v.y; s2 += v.z;
    }

    const float cx = coords[m * 2];
    const float cy = coords[m * 2 + 1];
    const float inv = 1.f / s0;
    const float nx = alpha * (s1 * inv) + (1.f - alpha) * cx;
    const float ny = alpha * (s2 * inv) + (1.f - alpha) * cy;

    out[m * 2]     = nx;
    out[m * 2 + 1] = ny;
    out[2 * MM + m * 2]     = nx - cx;
    out[2 * MM + m * 2 + 1] = ny - cy;
}

extern "C" void kernel_launch(void* const* d_in, const int* in_sizes, int n_in,
                              void* d_out, int out_size, void* d_ws, size_t ws_size,
                              hipStream_t stream) {
    const float* latents   = (const float*)d_in[0];
    const float* coords    = (const float*)d_in[1];
    const float* Wq        = (const float*)d_in[2];
    const float* Wk        = (const float*)d_in[3];
    const float* alpha_raw = (const float*)d_in[4];
    // d_in[5] = layer_idx: selects weight set only; provided W's are the
    // pred_idx=1 params, so unused.

    char* ws = (char*)d_ws;
    __hip_bfloat16* qn   = (__hip_bfloat16*)ws;                                  // 8 MB (fragment-major)
    __hip_bfloat16* kn   = (__hip_bfloat16*)(ws + (size_t)8 * 1024 * 1024);      // 8 MB (fragment-major)
    __hip_bfloat16* wq_b = (__hip_bfloat16*)(ws + (size_t)16 * 1024 * 1024);     // 128 KB (swizzled)
    __hip_bfloat16* wk_b = (__hip_bfloat16*)(ws + (size_t)16 * 1024 * 1024 + 131072);
    float* partials      = (float*)(ws + (size_t)16 * 1024 * 1024 + 262144);     // 2 MB

    float* out = (float*)d_out;

    cvt_swz_kernel<<<64, 256, 0, stream>>>(Wq, Wk, (unsigned short*)wq_b, (unsigned short*)wk_b);
    proj_norm_kernel<<<512, 256, 0, stream>>>(latents, wq_b, wk_b, qn, kn);
    attn_kernel<<<BB * NQB * NSPLIT, 256, 0, stream>>>(qn, kn, coords, partials);
    finish_kernel<<<MM / 256, 256, 0, stream>>>(partials, coords, alpha_raw, out);
}